// Round 1
// baseline (7909.521 us; speedup 1.0000x reference)
//
#include <hip/hip_runtime.h>
#include <math.h>

constexpr int kN    = 100000;
constexpr int kDM   = 256;
constexpr int kDE   = 172;
constexpr int kDT   = 100;
constexpr int kDEMB = 256;
constexpr int kDH   = 128;   // DEMB / H
constexpr int kH    = 2;
constexpr int kU    = 50000;
constexpr int kNB   = 6000;
constexpr int kK    = 20;
constexpr int kMSG  = 784;               // 2*DM + DE + DT
constexpr int kQIN  = kDM + kDT;         // 356
constexpr int kKIN  = kDM + kDE + kDT;   // 528
constexpr int kZIN  = kDEMB + kDM;       // 512
constexpr int kGRU_R = 8;

__device__ __forceinline__ float sigmoidf_(float x){ return 1.0f/(1.0f+expf(-x)); }

__global__ __launch_bounds__(256) void copy_f4(const float4* __restrict__ src,
                                               float4* __restrict__ dst, int n4){
  int stride = gridDim.x * blockDim.x;
  for (int i = blockIdx.x*blockDim.x + threadIdx.x; i < n4; i += stride)
    dst[i] = src[i];
}

// One block computes h_new for kGRU_R unique rows; thread j owns output col j.
__global__ __launch_bounds__(256) void gru_kernel(
    const float* __restrict__ msg, const float* __restrict__ memory,
    const float* __restrict__ w_ih, const float* __restrict__ w_hh,
    const float* __restrict__ b_ih, const float* __restrict__ b_hh,
    const int* __restrict__ unids, float* __restrict__ mem_new)
{
  __shared__ float xs[kGRU_R][kMSG];
  __shared__ float hs[kGRU_R][kDM];
  __shared__ int   uid[kGRU_R];
  const int t = threadIdx.x;
  const int rowbase = blockIdx.x * kGRU_R;
  if (t < kGRU_R) uid[t] = unids[rowbase + t];
  __syncthreads();
  for (int r = 0; r < kGRU_R; ++r) {
    const float* src = msg + (size_t)(rowbase + r) * kMSG;
    for (int c = t; c < kMSG; c += 256) xs[r][c] = src[c];
    hs[r][t] = memory[(size_t)uid[r] * kDM + t];
  }
  __syncthreads();

  const int j = t;
  float air[kGRU_R], aiz[kGRU_R], ain[kGRU_R];
  float ahr[kGRU_R], ahz[kGRU_R], ahn[kGRU_R];
  #pragma unroll
  for (int r=0;r<kGRU_R;r++){ air[r]=aiz[r]=ain[r]=0.f; ahr[r]=ahz[r]=ahn[r]=0.f; }

  const float* wr = w_ih + (size_t)j * kMSG;
  const float* wz = w_ih + (size_t)(kDM + j) * kMSG;
  const float* wn = w_ih + (size_t)(2*kDM + j) * kMSG;
  for (int c = 0; c < kMSG; c += 4) {
    const float4 w4r = *(const float4*)(wr + c);
    const float4 w4z = *(const float4*)(wz + c);
    const float4 w4n = *(const float4*)(wn + c);
    #pragma unroll
    for (int r = 0; r < kGRU_R; ++r) {
      const float4 x4 = *(const float4*)(&xs[r][c]);
      air[r] += w4r.x*x4.x + w4r.y*x4.y + w4r.z*x4.z + w4r.w*x4.w;
      aiz[r] += w4z.x*x4.x + w4z.y*x4.y + w4z.z*x4.z + w4z.w*x4.w;
      ain[r] += w4n.x*x4.x + w4n.y*x4.y + w4n.z*x4.z + w4n.w*x4.w;
    }
  }
  const float* vr = w_hh + (size_t)j * kDM;
  const float* vz = w_hh + (size_t)(kDM + j) * kDM;
  const float* vn = w_hh + (size_t)(2*kDM + j) * kDM;
  for (int c = 0; c < kDM; c += 4) {
    const float4 w4r = *(const float4*)(vr + c);
    const float4 w4z = *(const float4*)(vz + c);
    const float4 w4n = *(const float4*)(vn + c);
    #pragma unroll
    for (int r = 0; r < kGRU_R; ++r) {
      const float4 h4 = *(const float4*)(&hs[r][c]);
      ahr[r] += w4r.x*h4.x + w4r.y*h4.y + w4r.z*h4.z + w4r.w*h4.w;
      ahz[r] += w4z.x*h4.x + w4z.y*h4.y + w4z.z*h4.z + w4z.w*h4.w;
      ahn[r] += w4n.x*h4.x + w4n.y*h4.y + w4n.z*h4.z + w4n.w*h4.w;
    }
  }
  const float bir = b_ih[j], biz = b_ih[kDM+j], bin_ = b_ih[2*kDM+j];
  const float bhr = b_hh[j], bhz = b_hh[kDM+j], bhn = b_hh[2*kDM+j];
  #pragma unroll
  for (int r = 0; r < kGRU_R; ++r) {
    const float rg = sigmoidf_(air[r]+bir + ahr[r]+bhr);
    const float zg = sigmoidf_(aiz[r]+biz + ahz[r]+bhz);
    const float ng = tanhf(ain[r]+bin_ + rg*(ahn[r]+bhn));
    mem_new[(size_t)uid[r]*kDM + j] = (1.f - zg)*ng + zg*hs[r][j];
  }
}

// One block per batch row n: builds k_in in LDS, computes q/k/v, attention,
// softmax, attn_out, and the fused z = relu([attn_out, node_feat] @ w_out.T + b).
__global__ __launch_bounds__(256) void attn_kernel(
    const float* __restrict__ mem_new, const float* __restrict__ last_upd,
    const float* __restrict__ times, const float* __restrict__ nbr_times,
    const float* __restrict__ nbr_feats,
    const float* __restrict__ t2v_w, const float* __restrict__ t2v_b,
    const float* __restrict__ w_q, const float* __restrict__ w_k,
    const float* __restrict__ w_v, const float* __restrict__ w_out,
    const float* __restrict__ b_out,
    const int* __restrict__ nids, const int* __restrict__ nbr_nids,
    const int* __restrict__ nbr_mask, float* __restrict__ z_out)
{
  __shared__ float kin[kK][kKIN];    // 42240 B
  __shared__ float kf[kK][kDEMB];    // 20480 B
  __shared__ float vf[kK][kDEMB];    // 20480 B
  __shared__ float qin[kQIN];
  __shared__ float qv[kDEMB];
  __shared__ float nf[kDM];
  __shared__ float dlt[kK];
  __shared__ int   nb[kK];
  __shared__ float red[kH*kK];
  __shared__ float attnw[kH][kK];
  __shared__ float ao[kDEMB];

  const int n = blockIdx.x;
  const int t = threadIdx.x;
  const int nid = nids[n];

  {
    const float v = mem_new[(size_t)nid*kDM + t];
    nf[t] = v; qin[t] = v;
  }
  if (t < kDT) qin[kDM + t] = cosf(t2v_b[t]);           // t2v of t=0
  if (t < kK) {
    nb[t]  = nbr_nids[(size_t)n*kK + t];
    dlt[t] = nbr_times[(size_t)n*kK + t] - (times[n] - last_upd[nid]);
  }
  __syncthreads();

  for (int idx = t; idx < kK*kKIN; idx += 256) {
    const int k = idx / kKIN;
    const int c = idx - k*kKIN;
    float v;
    if (c < kDM)          v = mem_new[(size_t)nb[k]*kDM + c];
    else if (c < kDM+kDE) v = nbr_feats[((size_t)n*kK + k)*kDE + (c - kDM)];
    else { const int d = c - kDM - kDE; v = cosf(dlt[k]*t2v_w[d] + t2v_b[d]); }
    kin[k][c] = v;
  }
  __syncthreads();

  { // q projection: thread t owns output col t
    float acc = 0.f;
    const float* wq = w_q + (size_t)t * kQIN;
    for (int c = 0; c < kQIN; c += 4) {
      const float4 w4 = *(const float4*)(wq + c);
      acc += w4.x*qin[c] + w4.y*qin[c+1] + w4.z*qin[c+2] + w4.w*qin[c+3];
    }
    qv[t] = acc;
  }

  { // k & v projections for all 20 neighbors: thread t owns col t
    float accK[kK], accV[kK];
    #pragma unroll
    for (int k=0;k<kK;k++){ accK[k]=0.f; accV[k]=0.f; }
    const float* wk = w_k + (size_t)t * kKIN;
    const float* wv = w_v + (size_t)t * kKIN;
    for (int c = 0; c < kKIN; c += 4) {
      const float4 k4 = *(const float4*)(wk + c);
      const float4 v4 = *(const float4*)(wv + c);
      #pragma unroll
      for (int k=0;k<kK;k++){
        const float4 x4 = *(const float4*)(&kin[k][c]);
        accK[k] += k4.x*x4.x + k4.y*x4.y + k4.z*x4.z + k4.w*x4.w;
        accV[k] += v4.x*x4.x + v4.y*x4.y + v4.z*x4.z + v4.w*x4.w;
      }
    }
    #pragma unroll
    for (int k=0;k<kK;k++){ kf[k][t]=accK[k]; vf[k][t]=accV[k]; }
  }
  __syncthreads();

  { // scores: 40 (h,k) pairs over 4 waves; dot over dh=128 per pair
    const int w = t >> 6, lane = t & 63;
    for (int i = 0; i < 10; ++i) {
      const int p = w*10 + i;
      const int h = p / kK, k = p - (p/kK)*kK;
      const int base = h*kDH;
      float s = qv[base+lane]*kf[k][base+lane] + qv[base+64+lane]*kf[k][base+64+lane];
      #pragma unroll
      for (int off=32; off; off>>=1) s += __shfl_xor(s, off, 64);
      if (lane == 0) {
        s *= 0.08838834764831845f;   // 1/sqrt(128)
        red[p] = (nbr_mask[(size_t)n*kK + k] > 0) ? s : -1e9f;
      }
    }
  }
  __syncthreads();

  if (t < kH) { // softmax over K=20, one thread per head
    float m = -1e30f;
    for (int k=0;k<kK;k++) m = fmaxf(m, red[t*kK+k]);
    float e[kK]; float ssum = 0.f;
    for (int k=0;k<kK;k++){ e[k] = expf(red[t*kK+k]-m); ssum += e[k]; }
    const float inv = 1.f/ssum;
    for (int k=0;k<kK;k++) attnw[t][k] = e[k]*inv;
  }
  __syncthreads();

  { // attn_out
    const int h = t >> 7;
    float acc = 0.f;
    #pragma unroll
    for (int k=0;k<kK;k++) acc += attnw[h][k]*vf[k][t];
    ao[t] = acc;
  }
  __syncthreads();

  { // z = relu([ao, nf] @ w_out.T + b_out)
    float acc = b_out[t];
    const float* wo = w_out + (size_t)t*kZIN;
    for (int c = 0; c < kDEMB; c += 4) {
      const float4 w4 = *(const float4*)(wo + c);
      acc += w4.x*ao[c] + w4.y*ao[c+1] + w4.z*ao[c+2] + w4.w*ao[c+3];
    }
    for (int c = 0; c < kDM; c += 4) {
      const float4 w4 = *(const float4*)(wo + kDEMB + c);
      acc += w4.x*nf[c] + w4.y*nf[c+1] + w4.z*nf[c+2] + w4.w*nf[c+3];
    }
    z_out[(size_t)n*kDEMB + t] = fmaxf(acc, 0.f);
  }
}

// grid 4000: b in [0,2000) -> pos pair (z_src[i], z_dst[i]); [2000,4000) -> neg.
__global__ __launch_bounds__(256) void lp_kernel(
    const float* __restrict__ z,
    const float* __restrict__ spw, const float* __restrict__ spb,
    const float* __restrict__ dpw, const float* __restrict__ dpb,
    const float* __restrict__ opw, const float* __restrict__ opb,
    float* __restrict__ out)
{
  __shared__ float za[kDEMB], zb[kDEMB], wsum[4];
  const int b = blockIdx.x;
  const int neg = b / 2000;
  const int i = b - neg*2000;
  const int t = threadIdx.x;
  za[t] = z[(size_t)i*kDEMB + t];
  zb[t] = z[(size_t)(2000 + neg*2000 + i)*kDEMB + t];
  __syncthreads();
  float acc = spb[t] + dpb[t];
  const float* ws = spw + (size_t)t*kDEMB;
  const float* wd = dpw + (size_t)t*kDEMB;
  for (int c = 0; c < kDEMB; c += 4) {
    const float4 a4 = *(const float4*)(ws + c);
    const float4 d4 = *(const float4*)(wd + c);
    acc += a4.x*za[c] + a4.y*za[c+1] + a4.z*za[c+2] + a4.w*za[c+3];
    acc += d4.x*zb[c] + d4.y*zb[c+1] + d4.z*zb[c+2] + d4.w*zb[c+3];
  }
  float p = fmaxf(acc, 0.f) * opw[t];
  #pragma unroll
  for (int off=32; off; off>>=1) p += __shfl_xor(p, off, 64);
  if ((t & 63) == 0) wsum[t>>6] = p;
  __syncthreads();
  if (t == 0)
    out[b] = sigmoidf_(wsum[0]+wsum[1]+wsum[2]+wsum[3] + opb[0]);
}

extern "C" void kernel_launch(void* const* d_in, const int* in_sizes, int n_in,
                              void* d_out, int out_size, void* d_ws, size_t ws_size,
                              hipStream_t stream)
{
  const float* memory   = (const float*)d_in[0];
  const float* last_upd = (const float*)d_in[1];
  const float* umsg     = (const float*)d_in[2];
  const float* times    = (const float*)d_in[3];
  const float* nbr_t    = (const float*)d_in[4];
  const float* nbr_f    = (const float*)d_in[5];
  const float* t2v_w    = (const float*)d_in[6];
  const float* t2v_b    = (const float*)d_in[7];
  const float* gw_ih    = (const float*)d_in[8];
  const float* gw_hh    = (const float*)d_in[9];
  const float* gb_ih    = (const float*)d_in[10];
  const float* gb_hh    = (const float*)d_in[11];
  const float* w_q      = (const float*)d_in[12];
  const float* w_k      = (const float*)d_in[13];
  const float* w_v      = (const float*)d_in[14];
  const float* w_out    = (const float*)d_in[15];
  const float* b_out    = (const float*)d_in[16];
  const float* lp_sw    = (const float*)d_in[17];
  const float* lp_sb    = (const float*)d_in[18];
  const float* lp_dw    = (const float*)d_in[19];
  const float* lp_db    = (const float*)d_in[20];
  const float* lp_ow    = (const float*)d_in[21];
  const float* lp_ob    = (const float*)d_in[22];
  const int*   unids    = (const int*)d_in[23];
  const int*   nids     = (const int*)d_in[24];
  const int*   nbrn     = (const int*)d_in[25];
  const int*   nbrm     = (const int*)d_in[26];

  float* mem_new = (float*)d_ws;                       // 100000*256 f32
  float* z_buf   = mem_new + (size_t)kN * kDM;         // 6000*256 f32

  copy_f4<<<2048, 256, 0, stream>>>((const float4*)memory, (float4*)mem_new,
                                    kN*kDM/4);
  gru_kernel<<<kU/kGRU_R, 256, 0, stream>>>(umsg, memory, gw_ih, gw_hh,
                                            gb_ih, gb_hh, unids, mem_new);
  attn_kernel<<<kNB, 256, 0, stream>>>(mem_new, last_upd, times, nbr_t, nbr_f,
                                       t2v_w, t2v_b, w_q, w_k, w_v, w_out, b_out,
                                       nids, nbrn, nbrm, z_buf);
  lp_kernel<<<4000, 256, 0, stream>>>(z_buf, lp_sw, lp_sb, lp_dw, lp_db,
                                      lp_ow, lp_ob, (float*)d_out);
}

// Round 2
// 3401.591 us; speedup vs baseline: 2.3252x; 2.3252x over previous
//
#include <hip/hip_runtime.h>
#include <math.h>

constexpr int kN    = 100000;
constexpr int kDM   = 256;
constexpr int kDE   = 172;
constexpr int kDT   = 100;
constexpr int kDEMB = 256;
constexpr int kDH   = 128;   // DEMB / H
constexpr int kH    = 2;
constexpr int kU    = 50000;
constexpr int kNB   = 6000;
constexpr int kK    = 20;
constexpr int kMSG  = 784;               // 2*DM + DE + DT
constexpr int kQIN  = kDM + kDT;         // 356
constexpr int kKIN  = kDM + kDE + kDT;   // 528
constexpr int kZIN  = kDEMB + kDM;       // 512
constexpr int kGRU_R = 8;

constexpr int kMPAD = 50048;             // 391 * 128
constexpr int kKP1  = 832;               // 784 padded to 13*64
constexpr int kKP2  = 256;               // 4*64
constexpr int kGN   = 768;               // 3*DM gate columns

typedef __bf16 bf16x8 __attribute__((ext_vector_type(8)));
typedef float  f32x4  __attribute__((ext_vector_type(4)));

__device__ __forceinline__ float sigmoidf_(float x){ return 1.0f/(1.0f+expf(-x)); }

__device__ __forceinline__ unsigned short f2bf(float f){
  unsigned int u = __float_as_uint(f);
  unsigned int r = (u + 0x7FFFu + ((u >> 16) & 1u)) >> 16;
  return (unsigned short)r;
}

__global__ __launch_bounds__(256) void copy_f4(const float4* __restrict__ src,
                                               float4* __restrict__ dst, int n4){
  int stride = gridDim.x * blockDim.x;
  for (int i = blockIdx.x*blockDim.x + threadIdx.x; i < n4; i += stride)
    dst[i] = src[i];
}

// fp32 [vrows x vcols] (row stride sld) -> bf16 [drows x dld], zero-padded.
__global__ __launch_bounds__(256) void cvt_pad(const float* __restrict__ src,
    unsigned short* __restrict__ dst, int vrows, int vcols, int sld,
    int drows, int dld)
{
  const int g8 = dld >> 3;
  const int total = drows * g8;
  for (int i = blockIdx.x*blockDim.x + threadIdx.x; i < total;
       i += gridDim.x*blockDim.x) {
    const int r  = i / g8;
    const int c8 = (i - r*g8) << 3;
    unsigned short o[8];
    if (r < vrows && c8 < vcols) {
      const float* s = src + (size_t)r * sld + c8;
      const float4 a = *(const float4*)s;
      const float4 b = *(const float4*)(s + 4);
      o[0]=f2bf(a.x); o[1]=f2bf(a.y); o[2]=f2bf(a.z); o[3]=f2bf(a.w);
      o[4]=f2bf(b.x); o[5]=f2bf(b.y); o[6]=f2bf(b.z); o[7]=f2bf(b.w);
    } else {
      #pragma unroll
      for (int q=0;q<8;q++) o[q]=0;
    }
    uint4 pack = *(const uint4*)o;
    *(uint4*)(dst + (size_t)r*dld + c8) = pack;
  }
}

// gather memory[unids[r]] rows -> bf16 [drows x 256], zero pad rows >= vrows
__global__ __launch_bounds__(256) void gather_bf16(const float* __restrict__ memory,
    const int* __restrict__ unids, unsigned short* __restrict__ dst,
    int vrows, int drows)
{
  const int total = drows * 32;            // 32 groups of 8 per row
  for (int i = blockIdx.x*blockDim.x + threadIdx.x; i < total;
       i += gridDim.x*blockDim.x) {
    const int r  = i >> 5;
    const int c8 = (i & 31) << 3;
    unsigned short o[8];
    if (r < vrows) {
      const int uid = unids[r];
      const float* s = memory + (size_t)uid * kDM + c8;
      const float4 a = *(const float4*)s;
      const float4 b = *(const float4*)(s + 4);
      o[0]=f2bf(a.x); o[1]=f2bf(a.y); o[2]=f2bf(a.z); o[3]=f2bf(a.w);
      o[4]=f2bf(b.x); o[5]=f2bf(b.y); o[6]=f2bf(b.z); o[7]=f2bf(b.w);
    } else {
      #pragma unroll
      for (int q=0;q<8;q++) o[q]=0;
    }
    uint4 pack = *(const uint4*)o;
    *(uint4*)(dst + (size_t)r*kDM + c8) = pack;
  }
}

// C[M,768] f32 = A[M,lda] @ B[768,lda]^T, bf16 inputs, m97-style 128x128 tile.
__global__ __launch_bounds__(256) void gemm_bt(
    const unsigned short* __restrict__ A, const unsigned short* __restrict__ B,
    float* __restrict__ C, int lda, int ktiles)
{
  __shared__ unsigned short As[128*64];
  __shared__ unsigned short Bs[128*64];

  const int t    = threadIdx.x;
  const int lane = t & 63;
  const int wid  = t >> 6;
  const int wr   = wid >> 1, wc = wid & 1;
  const int mbase = (blockIdx.x / 6) * 128;
  const int nbase = (blockIdx.x % 6) * 128;

  f32x4 acc[4][4];
  #pragma unroll
  for (int mi=0;mi<4;mi++)
    #pragma unroll
    for (int ni=0;ni<4;ni++)
      acc[mi][ni] = (f32x4){0.f,0.f,0.f,0.f};

  const int lr = (lane & 15);
  const int lk = (lane >> 4) * 8;

  for (int kt = 0; kt < ktiles; ++kt) {
    const int k0 = kt * 64;
    // stage A and B tiles: 4 iters x 256 threads x 16B each
    #pragma unroll
    for (int it = 0; it < 4; ++it) {
      const int row = (t >> 3) + it * 32;
      const int col = (t & 7) * 8;
      const unsigned short* ga = A + (size_t)(mbase + row) * lda + k0 + col;
      const unsigned short* gb = B + (size_t)(nbase + row) * lda + k0 + col;
      char* la = (char*)As + it*4096 + t*16;
      char* lb = (char*)Bs + it*4096 + t*16;
      __builtin_amdgcn_global_load_lds(
          (const __attribute__((address_space(1))) void*)ga,
          (__attribute__((address_space(3))) void*)la, 16, 0, 0);
      __builtin_amdgcn_global_load_lds(
          (const __attribute__((address_space(1))) void*)gb,
          (__attribute__((address_space(3))) void*)lb, 16, 0, 0);
    }
    __syncthreads();

    #pragma unroll
    for (int kk = 0; kk < 64; kk += 32) {
      bf16x8 af[4], bf[4];
      #pragma unroll
      for (int mi = 0; mi < 4; ++mi)
        af[mi] = *(const bf16x8*)(As + ((wr*64 + mi*16 + lr) * 64 + kk + lk));
      #pragma unroll
      for (int ni = 0; ni < 4; ++ni)
        bf[ni] = *(const bf16x8*)(Bs + ((wc*64 + ni*16 + lr) * 64 + kk + lk));
      #pragma unroll
      for (int mi = 0; mi < 4; ++mi)
        #pragma unroll
        for (int ni = 0; ni < 4; ++ni)
          acc[mi][ni] = __builtin_amdgcn_mfma_f32_16x16x32_bf16(
              af[mi], bf[ni], acc[mi][ni], 0, 0, 0);
    }
    __syncthreads();
  }

  // epilogue: C/D layout col = lane&15, row = (lane>>4)*4 + reg
  #pragma unroll
  for (int mi = 0; mi < 4; ++mi) {
    #pragma unroll
    for (int ni = 0; ni < 4; ++ni) {
      const int col = nbase + wc*64 + ni*16 + (lane & 15);
      #pragma unroll
      for (int r = 0; r < 4; ++r) {
        const int row = mbase + wr*64 + mi*16 + ((lane >> 4) << 2) + r;
        C[(size_t)row * kGN + col] = acc[mi][ni][r];
      }
    }
  }
}

// fused GRU gates from Gi (x@w_ih^T) and Gh (h@w_hh^T)
__global__ __launch_bounds__(256) void gru_gate(
    const float* __restrict__ Gi, const float* __restrict__ Gh,
    const float* __restrict__ memory, const float* __restrict__ b_ih,
    const float* __restrict__ b_hh, const int* __restrict__ unids,
    float* __restrict__ mem_new)
{
  const int i = blockIdx.x * 256 + threadIdx.x;
  const int r = i >> 8, j = i & 255;
  if (r >= kU) return;
  const size_t gb = (size_t)r * kGN;
  const float ir  = Gi[gb + j]       + b_ih[j];
  const float iz  = Gi[gb + 256 + j] + b_ih[256 + j];
  const float inn = Gi[gb + 512 + j] + b_ih[512 + j];
  const float hr  = Gh[gb + j]       + b_hh[j];
  const float hz  = Gh[gb + 256 + j] + b_hh[256 + j];
  const float hn  = Gh[gb + 512 + j] + b_hh[512 + j];
  const int uid = unids[r];
  const float h = memory[(size_t)uid*kDM + j];
  const float rg = sigmoidf_(ir + hr);
  const float zg = sigmoidf_(iz + hz);
  const float ng = tanhf(inn + rg * hn);
  mem_new[(size_t)uid*kDM + j] = (1.f - zg) * ng + zg * h;
}

// ---------------- fallback fp32 GRU (used only if ws too small) --------------
__global__ __launch_bounds__(256) void gru_kernel(
    const float* __restrict__ msg, const float* __restrict__ memory,
    const float* __restrict__ w_ih, const float* __restrict__ w_hh,
    const float* __restrict__ b_ih, const float* __restrict__ b_hh,
    const int* __restrict__ unids, float* __restrict__ mem_new)
{
  __shared__ float xs[kGRU_R][kMSG];
  __shared__ float hs[kGRU_R][kDM];
  __shared__ int   uid[kGRU_R];
  const int t = threadIdx.x;
  const int rowbase = blockIdx.x * kGRU_R;
  if (t < kGRU_R) uid[t] = unids[rowbase + t];
  __syncthreads();
  for (int r = 0; r < kGRU_R; ++r) {
    const float* src = msg + (size_t)(rowbase + r) * kMSG;
    for (int c = t; c < kMSG; c += 256) xs[r][c] = src[c];
    hs[r][t] = memory[(size_t)uid[r] * kDM + t];
  }
  __syncthreads();
  const int j = t;
  float air[kGRU_R], aiz[kGRU_R], ain[kGRU_R];
  float ahr[kGRU_R], ahz[kGRU_R], ahn[kGRU_R];
  #pragma unroll
  for (int r=0;r<kGRU_R;r++){ air[r]=aiz[r]=ain[r]=0.f; ahr[r]=ahz[r]=ahn[r]=0.f; }
  const float* wr = w_ih + (size_t)j * kMSG;
  const float* wz = w_ih + (size_t)(kDM + j) * kMSG;
  const float* wn = w_ih + (size_t)(2*kDM + j) * kMSG;
  for (int c = 0; c < kMSG; c += 4) {
    const float4 w4r = *(const float4*)(wr + c);
    const float4 w4z = *(const float4*)(wz + c);
    const float4 w4n = *(const float4*)(wn + c);
    #pragma unroll
    for (int r = 0; r < kGRU_R; ++r) {
      const float4 x4 = *(const float4*)(&xs[r][c]);
      air[r] += w4r.x*x4.x + w4r.y*x4.y + w4r.z*x4.z + w4r.w*x4.w;
      aiz[r] += w4z.x*x4.x + w4z.y*x4.y + w4z.z*x4.z + w4z.w*x4.w;
      ain[r] += w4n.x*x4.x + w4n.y*x4.y + w4n.z*x4.z + w4n.w*x4.w;
    }
  }
  const float* vr = w_hh + (size_t)j * kDM;
  const float* vz = w_hh + (size_t)(kDM + j) * kDM;
  const float* vn = w_hh + (size_t)(2*kDM + j) * kDM;
  for (int c = 0; c < kDM; c += 4) {
    const float4 w4r = *(const float4*)(vr + c);
    const float4 w4z = *(const float4*)(vz + c);
    const float4 w4n = *(const float4*)(vn + c);
    #pragma unroll
    for (int r = 0; r < kGRU_R; ++r) {
      const float4 h4 = *(const float4*)(&hs[r][c]);
      ahr[r] += w4r.x*h4.x + w4r.y*h4.y + w4r.z*h4.z + w4r.w*h4.w;
      ahz[r] += w4z.x*h4.x + w4z.y*h4.y + w4z.z*h4.z + w4z.w*h4.w;
      ahn[r] += w4n.x*h4.x + w4n.y*h4.y + w4n.z*h4.z + w4n.w*h4.w;
    }
  }
  const float bir = b_ih[j], biz = b_ih[kDM+j], bin_ = b_ih[2*kDM+j];
  const float bhr = b_hh[j], bhz = b_hh[kDM+j], bhn = b_hh[2*kDM+j];
  #pragma unroll
  for (int r = 0; r < kGRU_R; ++r) {
    const float rg = sigmoidf_(air[r]+bir + ahr[r]+bhr);
    const float zg = sigmoidf_(aiz[r]+biz + ahz[r]+bhz);
    const float ng = tanhf(ain[r]+bin_ + rg*(ahn[r]+bhn));
    mem_new[(size_t)uid[r]*kDM + j] = (1.f - zg)*ng + zg*hs[r][j];
  }
}

// ---------------- attention (unchanged from round 1) -------------------------
__global__ __launch_bounds__(256) void attn_kernel(
    const float* __restrict__ mem_new, const float* __restrict__ last_upd,
    const float* __restrict__ times, const float* __restrict__ nbr_times,
    const float* __restrict__ nbr_feats,
    const float* __restrict__ t2v_w, const float* __restrict__ t2v_b,
    const float* __restrict__ w_q, const float* __restrict__ w_k,
    const float* __restrict__ w_v, const float* __restrict__ w_out,
    const float* __restrict__ b_out,
    const int* __restrict__ nids, const int* __restrict__ nbr_nids,
    const int* __restrict__ nbr_mask, float* __restrict__ z_out)
{
  __shared__ float kin[kK][kKIN];
  __shared__ float kf[kK][kDEMB];
  __shared__ float vf[kK][kDEMB];
  __shared__ float qin[kQIN];
  __shared__ float qv[kDEMB];
  __shared__ float nf[kDM];
  __shared__ float dlt[kK];
  __shared__ int   nb[kK];
  __shared__ float red[kH*kK];
  __shared__ float attnw[kH][kK];
  __shared__ float ao[kDEMB];

  const int n = blockIdx.x;
  const int t = threadIdx.x;
  const int nid = nids[n];

  {
    const float v = mem_new[(size_t)nid*kDM + t];
    nf[t] = v; qin[t] = v;
  }
  if (t < kDT) qin[kDM + t] = cosf(t2v_b[t]);
  if (t < kK) {
    nb[t]  = nbr_nids[(size_t)n*kK + t];
    dlt[t] = nbr_times[(size_t)n*kK + t] - (times[n] - last_upd[nid]);
  }
  __syncthreads();

  for (int idx = t; idx < kK*kKIN; idx += 256) {
    const int k = idx / kKIN;
    const int c = idx - k*kKIN;
    float v;
    if (c < kDM)          v = mem_new[(size_t)nb[k]*kDM + c];
    else if (c < kDM+kDE) v = nbr_feats[((size_t)n*kK + k)*kDE + (c - kDM)];
    else { const int d = c - kDM - kDE; v = cosf(dlt[k]*t2v_w[d] + t2v_b[d]); }
    kin[k][c] = v;
  }
  __syncthreads();

  {
    float acc = 0.f;
    const float* wq = w_q + (size_t)t * kQIN;
    for (int c = 0; c < kQIN; c += 4) {
      const float4 w4 = *(const float4*)(wq + c);
      acc += w4.x*qin[c] + w4.y*qin[c+1] + w4.z*qin[c+2] + w4.w*qin[c+3];
    }
    qv[t] = acc;
  }

  {
    float accK[kK], accV[kK];
    #pragma unroll
    for (int k=0;k<kK;k++){ accK[k]=0.f; accV[k]=0.f; }
    const float* wk = w_k + (size_t)t * kKIN;
    const float* wv = w_v + (size_t)t * kKIN;
    for (int c = 0; c < kKIN; c += 4) {
      const float4 k4 = *(const float4*)(wk + c);
      const float4 v4 = *(const float4*)(wv + c);
      #pragma unroll
      for (int k=0;k<kK;k++){
        const float4 x4 = *(const float4*)(&kin[k][c]);
        accK[k] += k4.x*x4.x + k4.y*x4.y + k4.z*x4.z + k4.w*x4.w;
        accV[k] += v4.x*x4.x + v4.y*x4.y + v4.z*x4.z + v4.w*x4.w;
      }
    }
    #pragma unroll
    for (int k=0;k<kK;k++){ kf[k][t]=accK[k]; vf[k][t]=accV[k]; }
  }
  __syncthreads();

  {
    const int w = t >> 6, lane = t & 63;
    for (int i = 0; i < 10; ++i) {
      const int p = w*10 + i;
      const int h = p / kK, k = p - (p/kK)*kK;
      const int base = h*kDH;
      float s = qv[base+lane]*kf[k][base+lane] + qv[base+64+lane]*kf[k][base+64+lane];
      #pragma unroll
      for (int off=32; off; off>>=1) s += __shfl_xor(s, off, 64);
      if (lane == 0) {
        s *= 0.08838834764831845f;
        red[p] = (nbr_mask[(size_t)n*kK + k] > 0) ? s : -1e9f;
      }
    }
  }
  __syncthreads();

  if (t < kH) {
    float m = -1e30f;
    for (int k=0;k<kK;k++) m = fmaxf(m, red[t*kK+k]);
    float e[kK]; float ssum = 0.f;
    for (int k=0;k<kK;k++){ e[k] = expf(red[t*kK+k]-m); ssum += e[k]; }
    const float inv = 1.f/ssum;
    for (int k=0;k<kK;k++) attnw[t][k] = e[k]*inv;
  }
  __syncthreads();

  {
    const int h = t >> 7;
    float acc = 0.f;
    #pragma unroll
    for (int k=0;k<kK;k++) acc += attnw[h][k]*vf[k][t];
    ao[t] = acc;
  }
  __syncthreads();

  {
    float acc = b_out[t];
    const float* wo = w_out + (size_t)t*kZIN;
    for (int c = 0; c < kDEMB; c += 4) {
      const float4 w4 = *(const float4*)(wo + c);
      acc += w4.x*ao[c] + w4.y*ao[c+1] + w4.z*ao[c+2] + w4.w*ao[c+3];
    }
    for (int c = 0; c < kDM; c += 4) {
      const float4 w4 = *(const float4*)(wo + kDEMB + c);
      acc += w4.x*nf[c] + w4.y*nf[c+1] + w4.z*nf[c+2] + w4.w*nf[c+3];
    }
    z_out[(size_t)n*kDEMB + t] = fmaxf(acc, 0.f);
  }
}

__global__ __launch_bounds__(256) void lp_kernel(
    const float* __restrict__ z,
    const float* __restrict__ spw, const float* __restrict__ spb,
    const float* __restrict__ dpw, const float* __restrict__ dpb,
    const float* __restrict__ opw, const float* __restrict__ opb,
    float* __restrict__ out)
{
  __shared__ float za[kDEMB], zb[kDEMB], wsum[4];
  const int b = blockIdx.x;
  const int neg = b / 2000;
  const int i = b - neg*2000;
  const int t = threadIdx.x;
  za[t] = z[(size_t)i*kDEMB + t];
  zb[t] = z[(size_t)(2000 + neg*2000 + i)*kDEMB + t];
  __syncthreads();
  float acc = spb[t] + dpb[t];
  const float* ws = spw + (size_t)t*kDEMB;
  const float* wd = dpw + (size_t)t*kDEMB;
  for (int c = 0; c < kDEMB; c += 4) {
    const float4 a4 = *(const float4*)(ws + c);
    const float4 d4 = *(const float4*)(wd + c);
    acc += a4.x*za[c] + a4.y*za[c+1] + a4.z*za[c+2] + a4.w*za[c+3];
    acc += d4.x*zb[c] + d4.y*zb[c+1] + d4.z*zb[c+2] + d4.w*zb[c+3];
  }
  float p = fmaxf(acc, 0.f) * opw[t];
  #pragma unroll
  for (int off=32; off; off>>=1) p += __shfl_xor(p, off, 64);
  if ((t & 63) == 0) wsum[t>>6] = p;
  __syncthreads();
  if (t == 0)
    out[b] = sigmoidf_(wsum[0]+wsum[1]+wsum[2]+wsum[3] + opb[0]);
}

extern "C" void kernel_launch(void* const* d_in, const int* in_sizes, int n_in,
                              void* d_out, int out_size, void* d_ws, size_t ws_size,
                              hipStream_t stream)
{
  const float* memory   = (const float*)d_in[0];
  const float* last_upd = (const float*)d_in[1];
  const float* umsg     = (const float*)d_in[2];
  const float* times    = (const float*)d_in[3];
  const float* nbr_t    = (const float*)d_in[4];
  const float* nbr_f    = (const float*)d_in[5];
  const float* t2v_w    = (const float*)d_in[6];
  const float* t2v_b    = (const float*)d_in[7];
  const float* gw_ih    = (const float*)d_in[8];
  const float* gw_hh    = (const float*)d_in[9];
  const float* gb_ih    = (const float*)d_in[10];
  const float* gb_hh    = (const float*)d_in[11];
  const float* w_q      = (const float*)d_in[12];
  const float* w_k      = (const float*)d_in[13];
  const float* w_v      = (const float*)d_in[14];
  const float* w_out    = (const float*)d_in[15];
  const float* b_out    = (const float*)d_in[16];
  const float* lp_sw    = (const float*)d_in[17];
  const float* lp_sb    = (const float*)d_in[18];
  const float* lp_dw    = (const float*)d_in[19];
  const float* lp_db    = (const float*)d_in[20];
  const float* lp_ow    = (const float*)d_in[21];
  const float* lp_ob    = (const float*)d_in[22];
  const int*   unids    = (const int*)d_in[23];
  const int*   nids     = (const int*)d_in[24];
  const int*   nbrn     = (const int*)d_in[25];
  const int*   nbrm     = (const int*)d_in[26];

  char* ws = (char*)d_ws;
  float*          mem_new = (float*)ws;                          // 102,400,000 B
  float*          z_buf   = (float*)(ws + 102400000);            //   6,144,000 B
  unsigned short* A1      = (unsigned short*)(ws + 108544000);   //  83,279,872 B
  unsigned short* A2      = (unsigned short*)(ws + 191823872);   //  25,624,576 B
  unsigned short* W1b     = (unsigned short*)(ws + 217448448);   //   1,277,952 B
  unsigned short* W2b     = (unsigned short*)(ws + 218726400);   //     393,216 B
  float*          Gi      = (float*)(ws + 219119616);            // 153,747,456 B
  float*          Gh      = (float*)(ws + 372867072);            // 153,747,456 B
  constexpr size_t kNeed = 526614528;

  copy_f4<<<2048, 256, 0, stream>>>((const float4*)memory, (float4*)mem_new,
                                    kN*kDM/4);

  if (ws_size >= kNeed) {
    // bf16 conversions (padded)
    cvt_pad<<<2048, 256, 0, stream>>>(umsg, A1, kU, kMSG, kMSG, kMPAD, kKP1);
    gather_bf16<<<2048, 256, 0, stream>>>(memory, unids, A2, kU, kMPAD);
    cvt_pad<<<512, 256, 0, stream>>>(gw_ih, W1b, kGN, kMSG, kMSG, kGN, kKP1);
    cvt_pad<<<256, 256, 0, stream>>>(gw_hh, W2b, kGN, kDM, kDM, kGN, kKP2);
    // Gi = msg @ w_ih^T ; Gh = h @ w_hh^T
    gemm_bt<<<(kMPAD/128)*6, 256, 0, stream>>>(A1, W1b, Gi, kKP1, kKP1/64);
    gemm_bt<<<(kMPAD/128)*6, 256, 0, stream>>>(A2, W2b, Gh, kKP2, kKP2/64);
    gru_gate<<<kU, 256, 0, stream>>>(Gi, Gh, memory, gb_ih, gb_hh, unids, mem_new);
  } else {
    gru_kernel<<<kU/kGRU_R, 256, 0, stream>>>(umsg, memory, gw_ih, gw_hh,
                                              gb_ih, gb_hh, unids, mem_new);
  }

  attn_kernel<<<kNB, 256, 0, stream>>>(mem_new, last_upd, times, nbr_t, nbr_f,
                                       t2v_w, t2v_b, w_q, w_k, w_v, w_out, b_out,
                                       nids, nbrn, nbrm, z_buf);
  lp_kernel<<<4000, 256, 0, stream>>>(z_buf, lp_sw, lp_sb, lp_dw, lp_db,
                                      lp_ow, lp_ob, (float*)d_out);
}

// Round 3
// 1009.007 us; speedup vs baseline: 7.8389x; 3.3712x over previous
//
#include <hip/hip_runtime.h>
#include <math.h>

constexpr int kN    = 100000;
constexpr int kDM   = 256;
constexpr int kDE   = 172;
constexpr int kDT   = 100;
constexpr int kDEMB = 256;
constexpr int kDH   = 128;
constexpr int kH    = 2;
constexpr int kU    = 50000;
constexpr int kNB   = 6000;
constexpr int kK    = 20;
constexpr int kMSG  = 784;
constexpr int kQIN  = kDM + kDT;         // 356
constexpr int kKIN  = kDM + kDE + kDT;   // 528
constexpr int kZIN  = kDEMB + kDM;       // 512
constexpr int kGRU_R = 8;

constexpr int kMPAD = 50048;             // 391*128 (GRU M)
constexpr int kKP1  = 832;               // msg K padded
constexpr int kKP2  = 256;
constexpr int kGN   = 768;

constexpr int kNKROWS = kNB * kK;        // 120000
constexpr int kNKPAD  = 120064;          // 938*128
constexpr int kKINP   = 576;             // 528 -> 9*64
constexpr int kQINP   = 384;             // 356 -> 6*64
constexpr int kNBPAD  = 6016;            // 47*128

typedef __bf16 bf16x8 __attribute__((ext_vector_type(8)));
typedef float  f32x4  __attribute__((ext_vector_type(4)));

__device__ __forceinline__ float sigmoidf_(float x){ return 1.0f/(1.0f+expf(-x)); }

__device__ __forceinline__ unsigned short f2bf(float f){
  unsigned int u = __float_as_uint(f);
  unsigned int r = (u + 0x7FFFu + ((u >> 16) & 1u)) >> 16;
  return (unsigned short)r;
}
__device__ __forceinline__ float bf2f(unsigned short u){
  return __uint_as_float(((unsigned int)u) << 16);
}

__global__ __launch_bounds__(256) void copy_f4(const float4* __restrict__ src,
                                               float4* __restrict__ dst, int n4){
  int stride = gridDim.x * blockDim.x;
  for (int i = blockIdx.x*blockDim.x + threadIdx.x; i < n4; i += stride)
    dst[i] = src[i];
}

// fp32 [vrows x vcols] (row stride sld) -> bf16 [drows x dld], zero-padded.
// Tail-safe: straddling groups fall back to per-element with bounds check.
__global__ __launch_bounds__(256) void cvt_pad(const float* __restrict__ src,
    unsigned short* __restrict__ dst, int vrows, int vcols, int sld,
    int drows, int dld)
{
  const int g8 = dld >> 3;
  const int total = drows * g8;
  for (int i = blockIdx.x*blockDim.x + threadIdx.x; i < total;
       i += gridDim.x*blockDim.x) {
    const int r  = i / g8;
    const int c8 = (i - r*g8) << 3;
    unsigned short o[8];
    if (r < vrows && c8 + 7 < vcols) {
      const float* s = src + (size_t)r * sld + c8;
      const float4 a = *(const float4*)s;
      const float4 b = *(const float4*)(s + 4);
      o[0]=f2bf(a.x); o[1]=f2bf(a.y); o[2]=f2bf(a.z); o[3]=f2bf(a.w);
      o[4]=f2bf(b.x); o[5]=f2bf(b.y); o[6]=f2bf(b.z); o[7]=f2bf(b.w);
    } else if (r < vrows && c8 < vcols) {
      #pragma unroll
      for (int q=0;q<8;q++){
        const int col = c8 + q;
        o[q] = (col < vcols) ? f2bf(src[(size_t)r*sld + col]) : (unsigned short)0;
      }
    } else {
      #pragma unroll
      for (int q=0;q<8;q++) o[q]=0;
    }
    uint4 pack = *(const uint4*)o;
    *(uint4*)(dst + (size_t)r*dld + c8) = pack;
  }
}

__global__ __launch_bounds__(256) void gather_bf16(const float* __restrict__ memory,
    const int* __restrict__ unids, unsigned short* __restrict__ dst,
    int vrows, int drows)
{
  const int total = drows * 32;
  for (int i = blockIdx.x*blockDim.x + threadIdx.x; i < total;
       i += gridDim.x*blockDim.x) {
    const int r  = i >> 5;
    const int c8 = (i & 31) << 3;
    unsigned short o[8];
    if (r < vrows) {
      const int uid = unids[r];
      const float* s = memory + (size_t)uid * kDM + c8;
      const float4 a = *(const float4*)s;
      const float4 b = *(const float4*)(s + 4);
      o[0]=f2bf(a.x); o[1]=f2bf(a.y); o[2]=f2bf(a.z); o[3]=f2bf(a.w);
      o[4]=f2bf(b.x); o[5]=f2bf(b.y); o[6]=f2bf(b.z); o[7]=f2bf(b.w);
    } else {
      #pragma unroll
      for (int q=0;q<8;q++) o[q]=0;
    }
    uint4 pack = *(const uint4*)o;
    *(uint4*)(dst + (size_t)r*kDM + c8) = pack;
  }
}

// Generic bf16 GEMM: C[M,ldc] = A[M,lda] @ B[N,lda]^T (+bias, relu), m97 tile.
// grid = (M/128) * nblk, 256 threads.
template<int OUT_BF16, int RELU>
__global__ __launch_bounds__(256) void gemm_bt(
    const unsigned short* __restrict__ A, const unsigned short* __restrict__ B,
    void* __restrict__ Cv, const float* __restrict__ bias,
    int lda, int ktiles, int nblk, int ldc)
{
  __shared__ unsigned short As[128*64];
  __shared__ unsigned short Bs[128*64];

  const int t    = threadIdx.x;
  const int lane = t & 63;
  const int wid  = t >> 6;
  const int wr   = wid >> 1, wc = wid & 1;
  const int mbase = (blockIdx.x / nblk) * 128;
  const int nbase = (blockIdx.x % nblk) * 128;

  f32x4 acc[4][4];
  #pragma unroll
  for (int mi=0;mi<4;mi++)
    #pragma unroll
    for (int ni=0;ni<4;ni++)
      acc[mi][ni] = (f32x4){0.f,0.f,0.f,0.f};

  const int lr = (lane & 15);
  const int lk = (lane >> 4) * 8;

  for (int kt = 0; kt < ktiles; ++kt) {
    const int k0 = kt * 64;
    #pragma unroll
    for (int it = 0; it < 4; ++it) {
      const int row = (t >> 3) + it * 32;
      const int col = (t & 7) * 8;
      const unsigned short* ga = A + (size_t)(mbase + row) * lda + k0 + col;
      const unsigned short* gb = B + (size_t)(nbase + row) * lda + k0 + col;
      char* la = (char*)As + it*4096 + t*16;
      char* lb = (char*)Bs + it*4096 + t*16;
      __builtin_amdgcn_global_load_lds(
          (const __attribute__((address_space(1))) void*)ga,
          (__attribute__((address_space(3))) void*)la, 16, 0, 0);
      __builtin_amdgcn_global_load_lds(
          (const __attribute__((address_space(1))) void*)gb,
          (__attribute__((address_space(3))) void*)lb, 16, 0, 0);
    }
    __syncthreads();

    #pragma unroll
    for (int kk = 0; kk < 64; kk += 32) {
      bf16x8 af[4], bf_[4];
      #pragma unroll
      for (int mi = 0; mi < 4; ++mi)
        af[mi] = *(const bf16x8*)(As + ((wr*64 + mi*16 + lr) * 64 + kk + lk));
      #pragma unroll
      for (int ni = 0; ni < 4; ++ni)
        bf_[ni] = *(const bf16x8*)(Bs + ((wc*64 + ni*16 + lr) * 64 + kk + lk));
      #pragma unroll
      for (int mi = 0; mi < 4; ++mi)
        #pragma unroll
        for (int ni = 0; ni < 4; ++ni)
          acc[mi][ni] = __builtin_amdgcn_mfma_f32_16x16x32_bf16(
              af[mi], bf_[ni], acc[mi][ni], 0, 0, 0);
    }
    __syncthreads();
  }

  #pragma unroll
  for (int mi = 0; mi < 4; ++mi) {
    #pragma unroll
    for (int ni = 0; ni < 4; ++ni) {
      const int col = nbase + wc*64 + ni*16 + (lane & 15);
      const float bv = bias ? bias[col] : 0.f;
      #pragma unroll
      for (int r = 0; r < 4; ++r) {
        const int row = mbase + wr*64 + mi*16 + ((lane >> 4) << 2) + r;
        float v = acc[mi][ni][r] + bv;
        if (RELU) v = fmaxf(v, 0.f);
        if (OUT_BF16)
          ((unsigned short*)Cv)[(size_t)row * ldc + col] = f2bf(v);
        else
          ((float*)Cv)[(size_t)row * ldc + col] = v;
      }
    }
  }
}

__global__ __launch_bounds__(256) void gru_gate(
    const float* __restrict__ Gi, const float* __restrict__ Gh,
    const float* __restrict__ memory, const float* __restrict__ b_ih,
    const float* __restrict__ b_hh, const int* __restrict__ unids,
    float* __restrict__ mem_new)
{
  const int r = blockIdx.x, j = threadIdx.x;
  if (r >= kU) return;
  const size_t gb = (size_t)r * kGN;
  const float ir  = Gi[gb + j]       + b_ih[j];
  const float iz  = Gi[gb + 256 + j] + b_ih[256 + j];
  const float inn = Gi[gb + 512 + j] + b_ih[512 + j];
  const float hr  = Gh[gb + j]       + b_hh[j];
  const float hz  = Gh[gb + 256 + j] + b_hh[256 + j];
  const float hn  = Gh[gb + 512 + j] + b_hh[512 + j];
  const int uid = unids[r];
  const float h = memory[(size_t)uid*kDM + j];
  const float rg = sigmoidf_(ir + hr);
  const float zg = sigmoidf_(iz + hz);
  const float ng = tanhf(inn + rg * hn);
  mem_new[(size_t)uid*kDM + j] = (1.f - zg) * ng + zg * h;
}

// k_in rows [NKPAD x 576] bf16: [mem(256) | feats(172) | t2v(100) | 0...]
__global__ __launch_bounds__(256) void build_kin(
    const float* __restrict__ mem_new, const float* __restrict__ last_upd,
    const float* __restrict__ times, const float* __restrict__ nbr_times,
    const float* __restrict__ nbr_feats,
    const float* __restrict__ t2v_w, const float* __restrict__ t2v_b,
    const int* __restrict__ nids, const int* __restrict__ nbr_nids,
    unsigned short* __restrict__ kin)
{
  constexpr int g8 = kKINP >> 3;  // 72
  const int total = kNKPAD * g8;
  for (int i = blockIdx.x*blockDim.x + threadIdx.x; i < total;
       i += gridDim.x*blockDim.x) {
    const int r  = i / g8;
    const int c8 = (i - r*g8) << 3;
    unsigned short o[8];
    if (r >= kNKROWS) {
      #pragma unroll
      for (int q=0;q<8;q++) o[q]=0;
    } else {
      const int n = r / kK, k = r - n*kK;
      if (c8 + 8 <= kDM) {
        const int nb = nbr_nids[(size_t)n*kK + k];
        const float* s = mem_new + (size_t)nb*kDM + c8;
        const float4 a = *(const float4*)s;
        const float4 b = *(const float4*)(s + 4);
        o[0]=f2bf(a.x); o[1]=f2bf(a.y); o[2]=f2bf(a.z); o[3]=f2bf(a.w);
        o[4]=f2bf(b.x); o[5]=f2bf(b.y); o[6]=f2bf(b.z); o[7]=f2bf(b.w);
      } else if (c8 >= kDM && c8 + 8 <= kDM + kDE) {
        const float* s = nbr_feats + ((size_t)n*kK + k)*kDE + (c8 - kDM);
        const float4 a = *(const float4*)s;
        const float4 b = *(const float4*)(s + 4);
        o[0]=f2bf(a.x); o[1]=f2bf(a.y); o[2]=f2bf(a.z); o[3]=f2bf(a.w);
        o[4]=f2bf(b.x); o[5]=f2bf(b.y); o[6]=f2bf(b.z); o[7]=f2bf(b.w);
      } else {
        float dlt = 0.f;
        if (c8 + 8 > kDM + kDE && c8 < kKIN)
          dlt = nbr_times[(size_t)n*kK + k] - (times[n] - last_upd[nids[n]]);
        #pragma unroll
        for (int q=0;q<8;q++){
          const int c = c8 + q;
          float v = 0.f;
          if (c < kDM + kDE) v = nbr_feats[((size_t)n*kK + k)*kDE + (c - kDM)];
          else if (c < kKIN) {
            const int d = c - kDM - kDE;
            v = cosf(dlt*t2v_w[d] + t2v_b[d]);
          }
          o[q] = f2bf(v);
        }
      }
    }
    uint4 pack = *(const uint4*)o;
    *(uint4*)(kin + (size_t)r*kKINP + c8) = pack;
  }
}

// q_in rows [NBPAD x 384] bf16: [mem(256) | t2v0(100) | 0...]
__global__ __launch_bounds__(256) void build_qin(
    const float* __restrict__ mem_new, const float* __restrict__ t2v_b,
    const int* __restrict__ nids, unsigned short* __restrict__ qin)
{
  constexpr int g8 = kQINP >> 3;  // 48
  const int total = kNBPAD * g8;
  for (int i = blockIdx.x*blockDim.x + threadIdx.x; i < total;
       i += gridDim.x*blockDim.x) {
    const int r  = i / g8;
    const int c8 = (i - r*g8) << 3;
    unsigned short o[8];
    if (r >= kNB) {
      #pragma unroll
      for (int q=0;q<8;q++) o[q]=0;
    } else if (c8 + 8 <= kDM) {
      const float* s = mem_new + (size_t)nids[r]*kDM + c8;
      const float4 a = *(const float4*)s;
      const float4 b = *(const float4*)(s + 4);
      o[0]=f2bf(a.x); o[1]=f2bf(a.y); o[2]=f2bf(a.z); o[3]=f2bf(a.w);
      o[4]=f2bf(b.x); o[5]=f2bf(b.y); o[6]=f2bf(b.z); o[7]=f2bf(b.w);
    } else {
      #pragma unroll
      for (int q=0;q<8;q++){
        const int c = c8 + q;
        float v = 0.f;
        if (c >= kDM && c < kQIN) v = cosf(t2v_b[c - kDM]);
        o[q] = f2bf(v);
      }
    }
    uint4 pack = *(const uint4*)o;
    *(uint4*)(qin + (size_t)r*kQINP + c8) = pack;
  }
}

// Per-row attention core: scores -> softmax -> attn_out; emits [ao|nf] bf16.
__global__ __launch_bounds__(256) void attn2_kernel(
    const float* __restrict__ qv, const unsigned short* __restrict__ kvf,
    const unsigned short* __restrict__ qin, const int* __restrict__ nbr_mask,
    unsigned short* __restrict__ aonf)
{
  __shared__ unsigned short kv[kK][kZIN];   // 20 KiB (kf cols 0-255, vf 256-511)
  __shared__ float qv_s[kDEMB];
  __shared__ float red[kH*kK];
  __shared__ float attnw[kH][kK];

  const int n = blockIdx.x;
  const int t = threadIdx.x;

  qv_s[t] = qv[(size_t)n*kDEMB + t];
  {
    const uint4* src = (const uint4*)(kvf + (size_t)n*kK*kZIN);
    uint4* dst = (uint4*)(&kv[0][0]);
    #pragma unroll
    for (int i = 0; i < 5; ++i) dst[t + i*256] = src[t + i*256];
  }
  __syncthreads();

  {
    const int w = t >> 6, lane = t & 63;
    #pragma unroll
    for (int i = 0; i < 10; ++i) {
      const int p = w*10 + i;
      const int h = p / kK, k = p - (p/kK)*kK;
      const int base = h*kDH;
      float s = qv_s[base+lane]*bf2f(kv[k][base+lane])
              + qv_s[base+64+lane]*bf2f(kv[k][base+64+lane]);
      #pragma unroll
      for (int off=32; off; off>>=1) s += __shfl_xor(s, off, 64);
      if (lane == 0) {
        s *= 0.08838834764831845f;
        red[p] = (nbr_mask[(size_t)n*kK + k] > 0) ? s : -1e9f;
      }
    }
  }
  __syncthreads();

  if (t < kH) {
    float m = -1e30f;
    for (int k=0;k<kK;k++) m = fmaxf(m, red[t*kK+k]);
    float e[kK]; float ssum = 0.f;
    for (int k=0;k<kK;k++){ e[k] = expf(red[t*kK+k]-m); ssum += e[k]; }
    const float inv = 1.f/ssum;
    for (int k=0;k<kK;k++) attnw[t][k] = e[k]*inv;
  }
  __syncthreads();

  {
    const int h = t >> 7;
    float acc = 0.f;
    #pragma unroll
    for (int k=0;k<kK;k++) acc += attnw[h][k]*bf2f(kv[k][kDEMB + t]);
    aonf[(size_t)n*kZIN + t] = f2bf(acc);
    aonf[(size_t)n*kZIN + kDEMB + t] = qin[(size_t)n*kQINP + t];  // nf bf16
  }
}

__global__ __launch_bounds__(256) void lp_kernel(
    const float* __restrict__ z,
    const float* __restrict__ spw, const float* __restrict__ spb,
    const float* __restrict__ dpw, const float* __restrict__ dpb,
    const float* __restrict__ opw, const float* __restrict__ opb,
    float* __restrict__ out)
{
  __shared__ float za[kDEMB], zb[kDEMB], wsum[4];
  const int b = blockIdx.x;
  const int neg = b / 2000;
  const int i = b - neg*2000;
  const int t = threadIdx.x;
  za[t] = z[(size_t)i*kDEMB + t];
  zb[t] = z[(size_t)(2000 + neg*2000 + i)*kDEMB + t];
  __syncthreads();
  float acc = spb[t] + dpb[t];
  const float* ws = spw + (size_t)t*kDEMB;
  const float* wd = dpw + (size_t)t*kDEMB;
  for (int c = 0; c < kDEMB; c += 4) {
    const float4 a4 = *(const float4*)(ws + c);
    const float4 d4 = *(const float4*)(wd + c);
    acc += a4.x*za[c] + a4.y*za[c+1] + a4.z*za[c+2] + a4.w*za[c+3];
    acc += d4.x*zb[c] + d4.y*zb[c+1] + d4.z*zb[c+2] + d4.w*zb[c+3];
  }
  float p = fmaxf(acc, 0.f) * opw[t];
  #pragma unroll
  for (int off=32; off; off>>=1) p += __shfl_xor(p, off, 64);
  if ((t & 63) == 0) wsum[t>>6] = p;
  __syncthreads();
  if (t == 0)
    out[b] = sigmoidf_(wsum[0]+wsum[1]+wsum[2]+wsum[3] + opb[0]);
}

// ---------------- fallback fp32 kernels (small-ws path) ----------------------
__global__ __launch_bounds__(256) void gru_kernel(
    const float* __restrict__ msg, const float* __restrict__ memory,
    const float* __restrict__ w_ih, const float* __restrict__ w_hh,
    const float* __restrict__ b_ih, const float* __restrict__ b_hh,
    const int* __restrict__ unids, float* __restrict__ mem_new)
{
  __shared__ float xs[kGRU_R][kMSG];
  __shared__ float hs[kGRU_R][kDM];
  __shared__ int   uid[kGRU_R];
  const int t = threadIdx.x;
  const int rowbase = blockIdx.x * kGRU_R;
  if (t < kGRU_R) uid[t] = unids[rowbase + t];
  __syncthreads();
  for (int r = 0; r < kGRU_R; ++r) {
    const float* src = msg + (size_t)(rowbase + r) * kMSG;
    for (int c = t; c < kMSG; c += 256) xs[r][c] = src[c];
    hs[r][t] = memory[(size_t)uid[r] * kDM + t];
  }
  __syncthreads();
  const int j = t;
  float air[kGRU_R], aiz[kGRU_R], ain[kGRU_R];
  float ahr[kGRU_R], ahz[kGRU_R], ahn[kGRU_R];
  #pragma unroll
  for (int r=0;r<kGRU_R;r++){ air[r]=aiz[r]=ain[r]=0.f; ahr[r]=ahz[r]=ahn[r]=0.f; }
  const float* wr = w_ih + (size_t)j * kMSG;
  const float* wz = w_ih + (size_t)(kDM + j) * kMSG;
  const float* wn = w_ih + (size_t)(2*kDM + j) * kMSG;
  for (int c = 0; c < kMSG; c += 4) {
    const float4 w4r = *(const float4*)(wr + c);
    const float4 w4z = *(const float4*)(wz + c);
    const float4 w4n = *(const float4*)(wn + c);
    #pragma unroll
    for (int r = 0; r < kGRU_R; ++r) {
      const float4 x4 = *(const float4*)(&xs[r][c]);
      air[r] += w4r.x*x4.x + w4r.y*x4.y + w4r.z*x4.z + w4r.w*x4.w;
      aiz[r] += w4z.x*x4.x + w4z.y*x4.y + w4z.z*x4.z + w4z.w*x4.w;
      ain[r] += w4n.x*x4.x + w4n.y*x4.y + w4n.z*x4.z + w4n.w*x4.w;
    }
  }
  const float* vr = w_hh + (size_t)j * kDM;
  const float* vz = w_hh + (size_t)(kDM + j) * kDM;
  const float* vn = w_hh + (size_t)(2*kDM + j) * kDM;
  for (int c = 0; c < kDM; c += 4) {
    const float4 w4r = *(const float4*)(vr + c);
    const float4 w4z = *(const float4*)(vz + c);
    const float4 w4n = *(const float4*)(vn + c);
    #pragma unroll
    for (int r = 0; r < kGRU_R; ++r) {
      const float4 h4 = *(const float4*)(&hs[r][c]);
      ahr[r] += w4r.x*h4.x + w4r.y*h4.y + w4r.z*h4.z + w4r.w*h4.w;
      ahz[r] += w4z.x*h4.x + w4z.y*h4.y + w4z.z*h4.z + w4z.w*h4.w;
      ahn[r] += w4n.x*h4.x + w4n.y*h4.y + w4n.z*h4.z + w4n.w*h4.w;
    }
  }
  const float bir = b_ih[j], biz = b_ih[kDM+j], bin_ = b_ih[2*kDM+j];
  const float bhr = b_hh[j], bhz = b_hh[kDM+j], bhn = b_hh[2*kDM+j];
  #pragma unroll
  for (int r = 0; r < kGRU_R; ++r) {
    const float rg = sigmoidf_(air[r]+bir + ahr[r]+bhr);
    const float zg = sigmoidf_(aiz[r]+biz + ahz[r]+bhz);
    const float ng = tanhf(ain[r]+bin_ + rg*(ahn[r]+bhn));
    mem_new[(size_t)uid[r]*kDM + j] = (1.f - zg)*ng + zg*hs[r][j];
  }
}

__global__ __launch_bounds__(256) void attn_kernel(
    const float* __restrict__ mem_new, const float* __restrict__ last_upd,
    const float* __restrict__ times, const float* __restrict__ nbr_times,
    const float* __restrict__ nbr_feats,
    const float* __restrict__ t2v_w, const float* __restrict__ t2v_b,
    const float* __restrict__ w_q, const float* __restrict__ w_k,
    const float* __restrict__ w_v, const float* __restrict__ w_out,
    const float* __restrict__ b_out,
    const int* __restrict__ nids, const int* __restrict__ nbr_nids,
    const int* __restrict__ nbr_mask, float* __restrict__ z_out)
{
  __shared__ float kin[kK][kKIN];
  __shared__ float kf[kK][kDEMB];
  __shared__ float vf[kK][kDEMB];
  __shared__ float qin[kQIN];
  __shared__ float qvs[kDEMB];
  __shared__ float nf[kDM];
  __shared__ float dlt[kK];
  __shared__ int   nb[kK];
  __shared__ float red[kH*kK];
  __shared__ float attnw[kH][kK];
  __shared__ float ao[kDEMB];

  const int n = blockIdx.x;
  const int t = threadIdx.x;
  const int nid = nids[n];
  {
    const float v = mem_new[(size_t)nid*kDM + t];
    nf[t] = v; qin[t] = v;
  }
  if (t < kDT) qin[kDM + t] = cosf(t2v_b[t]);
  if (t < kK) {
    nb[t]  = nbr_nids[(size_t)n*kK + t];
    dlt[t] = nbr_times[(size_t)n*kK + t] - (times[n] - last_upd[nid]);
  }
  __syncthreads();
  for (int idx = t; idx < kK*kKIN; idx += 256) {
    const int k = idx / kKIN;
    const int c = idx - k*kKIN;
    float v;
    if (c < kDM)          v = mem_new[(size_t)nb[k]*kDM + c];
    else if (c < kDM+kDE) v = nbr_feats[((size_t)n*kK + k)*kDE + (c - kDM)];
    else { const int d = c - kDM - kDE; v = cosf(dlt[k]*t2v_w[d] + t2v_b[d]); }
    kin[k][c] = v;
  }
  __syncthreads();
  {
    float acc = 0.f;
    const float* wq = w_q + (size_t)t * kQIN;
    for (int c = 0; c < kQIN; c += 4) {
      const float4 w4 = *(const float4*)(wq + c);
      acc += w4.x*qin[c] + w4.y*qin[c+1] + w4.z*qin[c+2] + w4.w*qin[c+3];
    }
    qvs[t] = acc;
  }
  {
    float accK[kK], accV[kK];
    #pragma unroll
    for (int k=0;k<kK;k++){ accK[k]=0.f; accV[k]=0.f; }
    const float* wk = w_k + (size_t)t * kKIN;
    const float* wv = w_v + (size_t)t * kKIN;
    for (int c = 0; c < kKIN; c += 4) {
      const float4 k4 = *(const float4*)(wk + c);
      const float4 v4 = *(const float4*)(wv + c);
      #pragma unroll
      for (int k=0;k<kK;k++){
        const float4 x4 = *(const float4*)(&kin[k][c]);
        accK[k] += k4.x*x4.x + k4.y*x4.y + k4.z*x4.z + k4.w*x4.w;
        accV[k] += v4.x*x4.x + v4.y*x4.y + v4.z*x4.z + v4.w*x4.w;
      }
    }
    #pragma unroll
    for (int k=0;k<kK;k++){ kf[k][t]=accK[k]; vf[k][t]=accV[k]; }
  }
  __syncthreads();
  {
    const int w = t >> 6, lane = t & 63;
    for (int i = 0; i < 10; ++i) {
      const int p = w*10 + i;
      const int h = p / kK, k = p - (p/kK)*kK;
      const int base = h*kDH;
      float s = qvs[base+lane]*kf[k][base+lane] + qvs[base+64+lane]*kf[k][base+64+lane];
      #pragma unroll
      for (int off=32; off; off>>=1) s += __shfl_xor(s, off, 64);
      if (lane == 0) {
        s *= 0.08838834764831845f;
        red[p] = (nbr_mask[(size_t)n*kK + k] > 0) ? s : -1e9f;
      }
    }
  }
  __syncthreads();
  if (t < kH) {
    float m = -1e30f;
    for (int k=0;k<kK;k++) m = fmaxf(m, red[t*kK+k]);
    float e[kK]; float ssum = 0.f;
    for (int k=0;k<kK;k++){ e[k] = expf(red[t*kK+k]-m); ssum += e[k]; }
    const float inv = 1.f/ssum;
    for (int k=0;k<kK;k++) attnw[t][k] = e[k]*inv;
  }
  __syncthreads();
  {
    const int h = t >> 7;
    float acc = 0.f;
    #pragma unroll
    for (int k=0;k<kK;k++) acc += attnw[h][k]*vf[k][t];
    ao[t] = acc;
  }
  __syncthreads();
  {
    float acc = b_out[t];
    const float* wo = w_out + (size_t)t*kZIN;
    for (int c = 0; c < kDEMB; c += 4) {
      const float4 w4 = *(const float4*)(wo + c);
      acc += w4.x*ao[c] + w4.y*ao[c+1] + w4.z*ao[c+2] + w4.w*ao[c+3];
    }
    for (int c = 0; c < kDM; c += 4) {
      const float4 w4 = *(const float4*)(wo + kDEMB + c);
      acc += w4.x*nf[c] + w4.y*nf[c+1] + w4.z*nf[c+2] + w4.w*nf[c+3];
    }
    z_out[(size_t)n*kDEMB + t] = fmaxf(acc, 0.f);
  }
}

extern "C" void kernel_launch(void* const* d_in, const int* in_sizes, int n_in,
                              void* d_out, int out_size, void* d_ws, size_t ws_size,
                              hipStream_t stream)
{
  const float* memory   = (const float*)d_in[0];
  const float* last_upd = (const float*)d_in[1];
  const float* umsg     = (const float*)d_in[2];
  const float* times    = (const float*)d_in[3];
  const float* nbr_t    = (const float*)d_in[4];
  const float* nbr_f    = (const float*)d_in[5];
  const float* t2v_w    = (const float*)d_in[6];
  const float* t2v_b    = (const float*)d_in[7];
  const float* gw_ih    = (const float*)d_in[8];
  const float* gw_hh    = (const float*)d_in[9];
  const float* gb_ih    = (const float*)d_in[10];
  const float* gb_hh    = (const float*)d_in[11];
  const float* w_q      = (const float*)d_in[12];
  const float* w_k      = (const float*)d_in[13];
  const float* w_v      = (const float*)d_in[14];
  const float* w_out    = (const float*)d_in[15];
  const float* b_out    = (const float*)d_in[16];
  const float* lp_sw    = (const float*)d_in[17];
  const float* lp_sb    = (const float*)d_in[18];
  const float* lp_dw    = (const float*)d_in[19];
  const float* lp_db    = (const float*)d_in[20];
  const float* lp_ow    = (const float*)d_in[21];
  const float* lp_ob    = (const float*)d_in[22];
  const int*   unids    = (const int*)d_in[23];
  const int*   nids     = (const int*)d_in[24];
  const int*   nbrn     = (const int*)d_in[25];
  const int*   nbrm     = (const int*)d_in[26];

  char* ws = (char*)d_ws;
  float* mem_new = (float*)ws;                                  // 102,400,000 B

  // --- GRU staging region (dead after gru_gate) ---
  unsigned short* A1  = (unsigned short*)(ws + 102400000);      //  83,279,872
  unsigned short* A2  = (unsigned short*)(ws + 185679872);      //  25,624,576
  unsigned short* W1b = (unsigned short*)(ws + 211304448);      //   1,277,952
  unsigned short* W2b = (unsigned short*)(ws + 212582400);      //     393,216
  float*          Gi  = (float*)(ws + 212975616);               // 153,747,456
  float*          Gh  = (float*)(ws + 366723072);               // 153,747,456
  constexpr size_t kNeed = 520470528;                           // Gh end

  // --- attention staging (reuses the GRU region, launched after gru_gate) ---
  unsigned short* kin_bf  = (unsigned short*)(ws + 102400000);  // 138,313,728
  unsigned short* kvf_bf  = (unsigned short*)(ws + 240713728);  // 122,945,536
  unsigned short* qin_bf  = (unsigned short*)(ws + 363659264);  //   4,620,288
  float*          qv_f    = (float*)(ws + 368279552);           //   6,160,384
  unsigned short* wq_bf   = (unsigned short*)(ws + 374439936);  //     196,608
  unsigned short* wkv_bf  = (unsigned short*)(ws + 374636544);  //     589,824
  unsigned short* aonf_bf = (unsigned short*)(ws + 375226368);  //   6,160,384
  unsigned short* wo_bf   = (unsigned short*)(ws + 381386752);  //     262,144
  float*          z_buf   = (float*)(ws + 381648896);           //   6,160,384

  copy_f4<<<2048, 256, 0, stream>>>((const float4*)memory, (float4*)mem_new,
                                    kN*kDM/4);

  if (ws_size >= kNeed) {
    // --- GRU as bf16 MFMA GEMMs ---
    cvt_pad<<<2048, 256, 0, stream>>>(umsg, A1, kU, kMSG, kMSG, kMPAD, kKP1);
    gather_bf16<<<2048, 256, 0, stream>>>(memory, unids, A2, kU, kMPAD);
    cvt_pad<<<512, 256, 0, stream>>>(gw_ih, W1b, kGN, kMSG, kMSG, kGN, kKP1);
    cvt_pad<<<256, 256, 0, stream>>>(gw_hh, W2b, kGN, kDM, kDM, kGN, kKP2);
    gemm_bt<0,0><<<(kMPAD/128)*6, 256, 0, stream>>>(A1, W1b, Gi, nullptr,
                                                    kKP1, kKP1/64, 6, kGN);
    gemm_bt<0,0><<<(kMPAD/128)*6, 256, 0, stream>>>(A2, W2b, Gh, nullptr,
                                                    kKP2, kKP2/64, 6, kGN);
    gru_gate<<<kU, 256, 0, stream>>>(Gi, Gh, memory, gb_ih, gb_hh, unids, mem_new);

    // --- attention as staged GEMMs ---
    cvt_pad<<<64, 256, 0, stream>>>(w_q, wq_bf, kDEMB, kQIN, kQIN, kDEMB, kQINP);
    cvt_pad<<<128, 256, 0, stream>>>(w_k, wkv_bf, kDEMB, kKIN, kKIN, kDEMB, kKINP);
    cvt_pad<<<128, 256, 0, stream>>>(w_v, wkv_bf + (size_t)kDEMB*kKINP,
                                     kDEMB, kKIN, kKIN, kDEMB, kKINP);
    cvt_pad<<<64, 256, 0, stream>>>(w_out, wo_bf, kDEMB, kZIN, kZIN, kDEMB, kZIN);
    build_qin<<<1152, 256, 0, stream>>>(mem_new, t2v_b, nids, qin_bf);
    build_kin<<<4096, 256, 0, stream>>>(mem_new, last_upd, times, nbr_t, nbr_f,
                                        t2v_w, t2v_b, nids, nbrn, kin_bf);
    gemm_bt<0,0><<<(kNBPAD/128)*2, 256, 0, stream>>>(qin_bf, wq_bf, qv_f, nullptr,
                                                     kQINP, kQINP/64, 2, kDEMB);
    gemm_bt<1,0><<<(kNKPAD/128)*4, 256, 0, stream>>>(kin_bf, wkv_bf, kvf_bf,
                                                     nullptr, kKINP, kKINP/64,
                                                     4, kZIN);
    attn2_kernel<<<kNB, 256, 0, stream>>>(qv_f, kvf_bf, qin_bf, nbrm, aonf_bf);
    gemm_bt<0,1><<<(kNBPAD/128)*2, 256, 0, stream>>>(aonf_bf, wo_bf, z_buf, b_out,
                                                     kZIN, kZIN/64, 2, kDEMB);
    lp_kernel<<<4000, 256, 0, stream>>>(z_buf, lp_sw, lp_sb, lp_dw, lp_db,
                                        lp_ow, lp_ob, (float*)d_out);
  } else {
    // --- fallback fp32 path ---
    float* z_fb = (float*)(ws + 102400000);
    gru_kernel<<<kU/kGRU_R, 256, 0, stream>>>(umsg, memory, gw_ih, gw_hh,
                                              gb_ih, gb_hh, unids, mem_new);
    attn_kernel<<<kNB, 256, 0, stream>>>(mem_new, last_upd, times, nbr_t, nbr_f,
                                         t2v_w, t2v_b, w_q, w_k, w_v, w_out,
                                         b_out, nids, nbrn, nbrm, z_fb);
    lp_kernel<<<4000, 256, 0, stream>>>(z_fb, lp_sw, lp_sb, lp_dw, lp_db,
                                        lp_ow, lp_ob, (float*)d_out);
  }
}

// Round 4
// 746.968 us; speedup vs baseline: 10.5888x; 1.3508x over previous
//
#include <hip/hip_runtime.h>
#include <math.h>

constexpr int kN    = 100000;
constexpr int kDM   = 256;
constexpr int kDE   = 172;
constexpr int kDT   = 100;
constexpr int kDEMB = 256;
constexpr int kDH   = 128;
constexpr int kH    = 2;
constexpr int kU    = 50000;
constexpr int kNB   = 6000;
constexpr int kK    = 20;
constexpr int kMSG  = 784;
constexpr int kQIN  = kDM + kDT;         // 356
constexpr int kKIN  = kDM + kDE + kDT;   // 528
constexpr int kZIN  = kDEMB + kDM;       // 512
constexpr int kMPAD = 50048;             // 391*128 (GRU M)
constexpr int kKP1  = 832;               // msg K padded
constexpr int kKP2  = 256;
constexpr int kGN   = 768;

constexpr int kNKROWS = kNB * kK;        // 120000
constexpr int kNKPAD  = 120064;          // 938*128
constexpr int kKINP   = 576;             // 528 -> 9*64
constexpr int kQINP   = 384;             // 356 -> 6*64
constexpr int kNBPAD  = 6016;            // 47*128

typedef __bf16 bf16x8 __attribute__((ext_vector_type(8)));
typedef float  f32x4  __attribute__((ext_vector_type(4)));

__device__ __forceinline__ float sigmoidf_(float x){ return 1.0f/(1.0f+expf(-x)); }

__device__ __forceinline__ unsigned short f2bf(float f){
  unsigned int u = __float_as_uint(f);
  unsigned int r = (u + 0x7FFFu + ((u >> 16) & 1u)) >> 16;
  return (unsigned short)r;
}
__device__ __forceinline__ float bf2f(unsigned short u){
  return __uint_as_float(((unsigned int)u) << 16);
}

__global__ __launch_bounds__(256) void copy_f4(const float4* __restrict__ src,
                                               float4* __restrict__ dst, int n4){
  int stride = gridDim.x * blockDim.x;
  for (int i = blockIdx.x*blockDim.x + threadIdx.x; i < n4; i += stride)
    dst[i] = src[i];
}

// fp32 [vrows x vcols] (row stride sld) -> bf16 [drows x dld], zero-padded.
__global__ __launch_bounds__(256) void cvt_pad(const float* __restrict__ src,
    unsigned short* __restrict__ dst, int vrows, int vcols, int sld,
    int drows, int dld)
{
  const int g8 = dld >> 3;
  const int total = drows * g8;
  for (int i = blockIdx.x*blockDim.x + threadIdx.x; i < total;
       i += gridDim.x*blockDim.x) {
    const int r  = i / g8;
    const int c8 = (i - r*g8) << 3;
    unsigned short o[8];
    if (r < vrows && c8 + 7 < vcols) {
      const float* s = src + (size_t)r * sld + c8;
      const float4 a = *(const float4*)s;
      const float4 b = *(const float4*)(s + 4);
      o[0]=f2bf(a.x); o[1]=f2bf(a.y); o[2]=f2bf(a.z); o[3]=f2bf(a.w);
      o[4]=f2bf(b.x); o[5]=f2bf(b.y); o[6]=f2bf(b.z); o[7]=f2bf(b.w);
    } else if (r < vrows && c8 < vcols) {
      #pragma unroll
      for (int q=0;q<8;q++){
        const int col = c8 + q;
        o[q] = (col < vcols) ? f2bf(src[(size_t)r*sld + col]) : (unsigned short)0;
      }
    } else {
      #pragma unroll
      for (int q=0;q<8;q++) o[q]=0;
    }
    uint4 pack = *(const uint4*)o;
    *(uint4*)(dst + (size_t)r*dld + c8) = pack;
  }
}

__global__ __launch_bounds__(256) void gather_bf16(const float* __restrict__ memory,
    const int* __restrict__ unids, unsigned short* __restrict__ dst,
    int vrows, int drows)
{
  const int total = drows * 32;
  for (int i = blockIdx.x*blockDim.x + threadIdx.x; i < total;
       i += gridDim.x*blockDim.x) {
    const int r  = i >> 5;
    const int c8 = (i & 31) << 3;
    unsigned short o[8];
    if (r < vrows) {
      const int uid = unids[r];
      const float* s = memory + (size_t)uid * kDM + c8;
      const float4 a = *(const float4*)s;
      const float4 b = *(const float4*)(s + 4);
      o[0]=f2bf(a.x); o[1]=f2bf(a.y); o[2]=f2bf(a.z); o[3]=f2bf(a.w);
      o[4]=f2bf(b.x); o[5]=f2bf(b.y); o[6]=f2bf(b.z); o[7]=f2bf(b.w);
    } else {
      #pragma unroll
      for (int q=0;q<8;q++) o[q]=0;
    }
    uint4 pack = *(const uint4*)o;
    *(uint4*)(dst + (size_t)r*kDM + c8) = pack;
  }
}

// Generic bf16 GEMM: C[M,ldc] = A[M,lda] @ B[N,lda]^T (+bias, relu), m97 tile.
template<int OUT_BF16, int RELU>
__global__ __launch_bounds__(256) void gemm_bt(
    const unsigned short* __restrict__ A, const unsigned short* __restrict__ B,
    void* __restrict__ Cv, const float* __restrict__ bias,
    int lda, int ktiles, int nblk, int ldc)
{
  __shared__ unsigned short As[128*64];
  __shared__ unsigned short Bs[128*64];

  const int t    = threadIdx.x;
  const int lane = t & 63;
  const int wid  = t >> 6;
  const int wr   = wid >> 1, wc = wid & 1;
  const int mbase = (blockIdx.x / nblk) * 128;
  const int nbase = (blockIdx.x % nblk) * 128;

  f32x4 acc[4][4];
  #pragma unroll
  for (int mi=0;mi<4;mi++)
    #pragma unroll
    for (int ni=0;ni<4;ni++)
      acc[mi][ni] = (f32x4){0.f,0.f,0.f,0.f};

  const int lr = (lane & 15);
  const int lk = (lane >> 4) * 8;

  for (int kt = 0; kt < ktiles; ++kt) {
    const int k0 = kt * 64;
    #pragma unroll
    for (int it = 0; it < 4; ++it) {
      const int row = (t >> 3) + it * 32;
      const int col = (t & 7) * 8;
      const unsigned short* ga = A + (size_t)(mbase + row) * lda + k0 + col;
      const unsigned short* gb = B + (size_t)(nbase + row) * lda + k0 + col;
      char* la = (char*)As + it*4096 + t*16;
      char* lb = (char*)Bs + it*4096 + t*16;
      __builtin_amdgcn_global_load_lds(
          (const __attribute__((address_space(1))) void*)ga,
          (__attribute__((address_space(3))) void*)la, 16, 0, 0);
      __builtin_amdgcn_global_load_lds(
          (const __attribute__((address_space(1))) void*)gb,
          (__attribute__((address_space(3))) void*)lb, 16, 0, 0);
    }
    __syncthreads();

    #pragma unroll
    for (int kk = 0; kk < 64; kk += 32) {
      bf16x8 af[4], bf_[4];
      #pragma unroll
      for (int mi = 0; mi < 4; ++mi)
        af[mi] = *(const bf16x8*)(As + ((wr*64 + mi*16 + lr) * 64 + kk + lk));
      #pragma unroll
      for (int ni = 0; ni < 4; ++ni)
        bf_[ni] = *(const bf16x8*)(Bs + ((wc*64 + ni*16 + lr) * 64 + kk + lk));
      #pragma unroll
      for (int mi = 0; mi < 4; ++mi)
        #pragma unroll
        for (int ni = 0; ni < 4; ++ni)
          acc[mi][ni] = __builtin_amdgcn_mfma_f32_16x16x32_bf16(
              af[mi], bf_[ni], acc[mi][ni], 0, 0, 0);
    }
    __syncthreads();
  }

  #pragma unroll
  for (int mi = 0; mi < 4; ++mi) {
    #pragma unroll
    for (int ni = 0; ni < 4; ++ni) {
      const int col = nbase + wc*64 + ni*16 + (lane & 15);
      const float bv = bias ? bias[col] : 0.f;
      #pragma unroll
      for (int r = 0; r < 4; ++r) {
        const int row = mbase + wr*64 + mi*16 + ((lane >> 4) << 2) + r;
        float v = acc[mi][ni][r] + bv;
        if (RELU) v = fmaxf(v, 0.f);
        if (OUT_BF16)
          ((unsigned short*)Cv)[(size_t)row * ldc + col] = f2bf(v);
        else
          ((float*)Cv)[(size_t)row * ldc + col] = v;
      }
    }
  }
}

// fused GRU gates from bf16 Gi (x@w_ih^T) and Gh (h@w_hh^T)
__global__ __launch_bounds__(256) void gru_gate_bf(
    const unsigned short* __restrict__ Gi, const unsigned short* __restrict__ Gh,
    const float* __restrict__ memory, const float* __restrict__ b_ih,
    const float* __restrict__ b_hh, const int* __restrict__ unids,
    float* __restrict__ mem_new)
{
  const int r = blockIdx.x, j = threadIdx.x;
  const size_t gb = (size_t)r * kGN;
  const float ir  = bf2f(Gi[gb + j])       + b_ih[j];
  const float iz  = bf2f(Gi[gb + 256 + j]) + b_ih[256 + j];
  const float inn = bf2f(Gi[gb + 512 + j]) + b_ih[512 + j];
  const float hr  = bf2f(Gh[gb + j])       + b_hh[j];
  const float hz  = bf2f(Gh[gb + 256 + j]) + b_hh[256 + j];
  const float hn  = bf2f(Gh[gb + 512 + j]) + b_hh[512 + j];
  const int uid = unids[r];
  const float h = memory[(size_t)uid*kDM + j];
  const float rg = sigmoidf_(ir + hr);
  const float zg = sigmoidf_(iz + hz);
  const float ng = tanhf(inn + rg * hn);
  mem_new[(size_t)uid*kDM + j] = (1.f - zg) * ng + zg * h;
}

// k_in rows [NKPAD x 576] bf16: [mem(256) | feats(172) | t2v(100) | 0...]
__global__ __launch_bounds__(256) void build_kin(
    const float* __restrict__ mem_new, const float* __restrict__ last_upd,
    const float* __restrict__ times, const float* __restrict__ nbr_times,
    const float* __restrict__ nbr_feats,
    const float* __restrict__ t2v_w, const float* __restrict__ t2v_b,
    const int* __restrict__ nids, const int* __restrict__ nbr_nids,
    unsigned short* __restrict__ kin)
{
  constexpr int g8 = kKINP >> 3;  // 72
  const int total = kNKPAD * g8;
  for (int i = blockIdx.x*blockDim.x + threadIdx.x; i < total;
       i += gridDim.x*blockDim.x) {
    const int r  = i / g8;
    const int c8 = (i - r*g8) << 3;
    unsigned short o[8];
    if (r >= kNKROWS) {
      #pragma unroll
      for (int q=0;q<8;q++) o[q]=0;
    } else {
      const int n = r / kK, k = r - n*kK;
      if (c8 + 8 <= kDM) {
        const int nb = nbr_nids[(size_t)n*kK + k];
        const float* s = mem_new + (size_t)nb*kDM + c8;
        const float4 a = *(const float4*)s;
        const float4 b = *(const float4*)(s + 4);
        o[0]=f2bf(a.x); o[1]=f2bf(a.y); o[2]=f2bf(a.z); o[3]=f2bf(a.w);
        o[4]=f2bf(b.x); o[5]=f2bf(b.y); o[6]=f2bf(b.z); o[7]=f2bf(b.w);
      } else if (c8 >= kDM && c8 + 8 <= kDM + kDE) {
        const float* s = nbr_feats + ((size_t)n*kK + k)*kDE + (c8 - kDM);
        const float4 a = *(const float4*)s;
        const float4 b = *(const float4*)(s + 4);
        o[0]=f2bf(a.x); o[1]=f2bf(a.y); o[2]=f2bf(a.z); o[3]=f2bf(a.w);
        o[4]=f2bf(b.x); o[5]=f2bf(b.y); o[6]=f2bf(b.z); o[7]=f2bf(b.w);
      } else {
        float dlt = 0.f;
        if (c8 + 8 > kDM + kDE && c8 < kKIN)
          dlt = nbr_times[(size_t)n*kK + k] - (times[n] - last_upd[nids[n]]);
        #pragma unroll
        for (int q=0;q<8;q++){
          const int c = c8 + q;
          float v = 0.f;
          if (c < kDM + kDE) v = nbr_feats[((size_t)n*kK + k)*kDE + (c - kDM)];
          else if (c < kKIN) {
            const int d = c - kDM - kDE;
            v = cosf(dlt*t2v_w[d] + t2v_b[d]);
          }
          o[q] = f2bf(v);
        }
      }
    }
    uint4 pack = *(const uint4*)o;
    *(uint4*)(kin + (size_t)r*kKINP + c8) = pack;
  }
}

// q_in rows [NBPAD x 384] bf16: [mem(256) | t2v0(100) | 0...]
__global__ __launch_bounds__(256) void build_qin(
    const float* __restrict__ mem_new, const float* __restrict__ t2v_b,
    const int* __restrict__ nids, unsigned short* __restrict__ qin)
{
  constexpr int g8 = kQINP >> 3;  // 48
  const int total = kNBPAD * g8;
  for (int i = blockIdx.x*blockDim.x + threadIdx.x; i < total;
       i += gridDim.x*blockDim.x) {
    const int r  = i / g8;
    const int c8 = (i - r*g8) << 3;
    unsigned short o[8];
    if (r >= kNB) {
      #pragma unroll
      for (int q=0;q<8;q++) o[q]=0;
    } else if (c8 + 8 <= kDM) {
      const float* s = mem_new + (size_t)nids[r]*kDM + c8;
      const float4 a = *(const float4*)s;
      const float4 b = *(const float4*)(s + 4);
      o[0]=f2bf(a.x); o[1]=f2bf(a.y); o[2]=f2bf(a.z); o[3]=f2bf(a.w);
      o[4]=f2bf(b.x); o[5]=f2bf(b.y); o[6]=f2bf(b.z); o[7]=f2bf(b.w);
    } else {
      #pragma unroll
      for (int q=0;q<8;q++){
        const int c = c8 + q;
        float v = 0.f;
        if (c >= kDM && c < kQIN) v = cosf(t2v_b[c - kDM]);
        o[q] = f2bf(v);
      }
    }
    uint4 pack = *(const uint4*)o;
    *(uint4*)(qin + (size_t)r*kQINP + c8) = pack;
  }
}

// Per-row attention core: scores -> softmax -> attn_out; emits [ao|nf] bf16.
__global__ __launch_bounds__(256) void attn2_kernel(
    const float* __restrict__ qv, const unsigned short* __restrict__ kvf,
    const unsigned short* __restrict__ qin, const int* __restrict__ nbr_mask,
    unsigned short* __restrict__ aonf)
{
  __shared__ unsigned short kv[kK][kZIN];
  __shared__ float qv_s[kDEMB];
  __shared__ float red[kH*kK];
  __shared__ float attnw[kH][kK];

  const int n = blockIdx.x;
  const int t = threadIdx.x;

  qv_s[t] = qv[(size_t)n*kDEMB + t];
  {
    const uint4* src = (const uint4*)(kvf + (size_t)n*kK*kZIN);
    uint4* dst = (uint4*)(&kv[0][0]);
    #pragma unroll
    for (int i = 0; i < 5; ++i) dst[t + i*256] = src[t + i*256];
  }
  __syncthreads();

  {
    const int w = t >> 6, lane = t & 63;
    #pragma unroll
    for (int i = 0; i < 10; ++i) {
      const int p = w*10 + i;
      const int h = p / kK, k = p - (p/kK)*kK;
      const int base = h*kDH;
      float s = qv_s[base+lane]*bf2f(kv[k][base+lane])
              + qv_s[base+64+lane]*bf2f(kv[k][base+64+lane]);
      #pragma unroll
      for (int off=32; off; off>>=1) s += __shfl_xor(s, off, 64);
      if (lane == 0) {
        s *= 0.08838834764831845f;
        red[p] = (nbr_mask[(size_t)n*kK + k] > 0) ? s : -1e9f;
      }
    }
  }
  __syncthreads();

  if (t < kH) {
    float m = -1e30f;
    for (int k=0;k<kK;k++) m = fmaxf(m, red[t*kK+k]);
    float e[kK]; float ssum = 0.f;
    for (int k=0;k<kK;k++){ e[k] = expf(red[t*kK+k]-m); ssum += e[k]; }
    const float inv = 1.f/ssum;
    for (int k=0;k<kK;k++) attnw[t][k] = e[k]*inv;
  }
  __syncthreads();

  {
    const int h = t >> 7;
    float acc = 0.f;
    #pragma unroll
    for (int k=0;k<kK;k++) acc += attnw[h][k]*bf2f(kv[k][kDEMB + t]);
    aonf[(size_t)n*kZIN + t] = f2bf(acc);
    aonf[(size_t)n*kZIN + kDEMB + t] = qin[(size_t)n*kQINP + t];
  }
}

// Final link-pred: P[r][0:256]=z[r]@spw^T, P[r][256:512]=z[r]@dpw^T.
// out[b] = sigmoid(relu(P[src]+spb + P[oth].dpwpart+dpb) . opw + opb)
__global__ __launch_bounds__(256) void lp_small(
    const float* __restrict__ P, const float* __restrict__ spb,
    const float* __restrict__ dpb, const float* __restrict__ opw,
    const float* __restrict__ opb, float* __restrict__ out)
{
  __shared__ float wsum[4];
  const int b = blockIdx.x;
  const int neg = b / 2000;
  const int i = b - neg*2000;
  const int t = threadIdx.x;
  const int oth = 2000 + neg*2000 + i;
  float h = P[(size_t)i*kZIN + t] + spb[t] + P[(size_t)oth*kZIN + kDEMB + t] + dpb[t];
  float p = fmaxf(h, 0.f) * opw[t];
  #pragma unroll
  for (int off=32; off; off>>=1) p += __shfl_xor(p, off, 64);
  if ((t & 63) == 0) wsum[t>>6] = p;
  __syncthreads();
  if (t == 0)
    out[b] = sigmoidf_(wsum[0]+wsum[1]+wsum[2]+wsum[3] + opb[0]);
}

extern "C" void kernel_launch(void* const* d_in, const int* in_sizes, int n_in,
                              void* d_out, int out_size, void* d_ws, size_t ws_size,
                              hipStream_t stream)
{
  const float* memory   = (const float*)d_in[0];
  const float* last_upd = (const float*)d_in[1];
  const float* umsg     = (const float*)d_in[2];
  const float* times    = (const float*)d_in[3];
  const float* nbr_t    = (const float*)d_in[4];
  const float* nbr_f    = (const float*)d_in[5];
  const float* t2v_w    = (const float*)d_in[6];
  const float* t2v_b    = (const float*)d_in[7];
  const float* gw_ih    = (const float*)d_in[8];
  const float* gw_hh    = (const float*)d_in[9];
  const float* gb_ih    = (const float*)d_in[10];
  const float* gb_hh    = (const float*)d_in[11];
  const float* w_q      = (const float*)d_in[12];
  const float* w_k      = (const float*)d_in[13];
  const float* w_v      = (const float*)d_in[14];
  const float* w_out    = (const float*)d_in[15];
  const float* b_out    = (const float*)d_in[16];
  const float* lp_sw    = (const float*)d_in[17];
  const float* lp_sb    = (const float*)d_in[18];
  const float* lp_dw    = (const float*)d_in[19];
  const float* lp_db    = (const float*)d_in[20];
  const float* lp_ow    = (const float*)d_in[21];
  const float* lp_ob    = (const float*)d_in[22];
  const int*   unids    = (const int*)d_in[23];
  const int*   nids     = (const int*)d_in[24];
  const int*   nbrn     = (const int*)d_in[25];
  const int*   nbrm     = (const int*)d_in[26];

  char* ws = (char*)d_ws;
  float* mem_new = (float*)ws;                                  // 102,400,000 B

  // --- GRU staging region (dead after gru_gate_bf) ---
  unsigned short* A1    = (unsigned short*)(ws + 102400000);    //  83,279,872
  unsigned short* A2    = (unsigned short*)(ws + 185679872);    //  25,624,576
  unsigned short* W1b   = (unsigned short*)(ws + 211304448);    //   1,277,952
  unsigned short* W2b   = (unsigned short*)(ws + 212582400);    //     393,216
  unsigned short* Gi_bf = (unsigned short*)(ws + 212975616);    //  76,873,728
  unsigned short* Gh_bf = (unsigned short*)(ws + 289849344);    //  76,873,728
                                                                // end 366,723,072
  // --- attention staging (reuses the GRU region, after gru_gate_bf) ---
  unsigned short* kin_bf  = (unsigned short*)(ws + 102400000);  // 138,313,728
  unsigned short* kvf_bf  = (unsigned short*)(ws + 240713728);  // 122,945,536
  unsigned short* qin_bf  = (unsigned short*)(ws + 363659264);  //   4,620,288
  float*          qv_f    = (float*)(ws + 368279552);           //   6,160,384
  unsigned short* wq_bf   = (unsigned short*)(ws + 374439936);  //     196,608
  unsigned short* wkv_bf  = (unsigned short*)(ws + 374636544);  //     589,824
  unsigned short* aonf_bf = (unsigned short*)(ws + 375226368);  //   6,160,384
  unsigned short* wo_bf   = (unsigned short*)(ws + 381386752);  //     262,144
  unsigned short* z_bf    = (unsigned short*)(ws + 381648896);  //   3,080,192
  unsigned short* wlp_bf  = (unsigned short*)(ws + 384729088);  //     262,144
  float*          P_f     = (float*)(ws + 384991232);           //  12,320,768
                                                                // end 397,312,000
  copy_f4<<<2048, 256, 0, stream>>>((const float4*)memory, (float4*)mem_new,
                                    kN*kDM/4);

  // --- GRU as bf16 MFMA GEMMs ---
  cvt_pad<<<2048, 256, 0, stream>>>(umsg, A1, kU, kMSG, kMSG, kMPAD, kKP1);
  gather_bf16<<<2048, 256, 0, stream>>>(memory, unids, A2, kU, kMPAD);
  cvt_pad<<<512, 256, 0, stream>>>(gw_ih, W1b, kGN, kMSG, kMSG, kGN, kKP1);
  cvt_pad<<<256, 256, 0, stream>>>(gw_hh, W2b, kGN, kDM, kDM, kGN, kKP2);
  gemm_bt<1,0><<<(kMPAD/128)*6, 256, 0, stream>>>(A1, W1b, Gi_bf, nullptr,
                                                  kKP1, kKP1/64, 6, kGN);
  gemm_bt<1,0><<<(kMPAD/128)*6, 256, 0, stream>>>(A2, W2b, Gh_bf, nullptr,
                                                  kKP2, kKP2/64, 6, kGN);
  gru_gate_bf<<<kU, 256, 0, stream>>>(Gi_bf, Gh_bf, memory, gb_ih, gb_hh,
                                      unids, mem_new);

  // --- attention as staged GEMMs ---
  cvt_pad<<<64, 256, 0, stream>>>(w_q, wq_bf, kDEMB, kQIN, kQIN, kDEMB, kQINP);
  cvt_pad<<<128, 256, 0, stream>>>(w_k, wkv_bf, kDEMB, kKIN, kKIN, kDEMB, kKINP);
  cvt_pad<<<128, 256, 0, stream>>>(w_v, wkv_bf + (size_t)kDEMB*kKINP,
                                   kDEMB, kKIN, kKIN, kDEMB, kKINP);
  cvt_pad<<<64, 256, 0, stream>>>(w_out, wo_bf, kDEMB, kZIN, kZIN, kDEMB, kZIN);
  cvt_pad<<<32, 256, 0, stream>>>(lp_sw, wlp_bf, kDEMB, kDEMB, kDEMB,
                                  kDEMB, kDEMB);
  cvt_pad<<<32, 256, 0, stream>>>(lp_dw, wlp_bf + (size_t)kDEMB*kDEMB,
                                  kDEMB, kDEMB, kDEMB, kDEMB, kDEMB);
  build_qin<<<1152, 256, 0, stream>>>(mem_new, t2v_b, nids, qin_bf);
  build_kin<<<4096, 256, 0, stream>>>(mem_new, last_upd, times, nbr_t, nbr_f,
                                      t2v_w, t2v_b, nids, nbrn, kin_bf);
  gemm_bt<0,0><<<(kNBPAD/128)*2, 256, 0, stream>>>(qin_bf, wq_bf, qv_f, nullptr,
                                                   kQINP, kQINP/64, 2, kDEMB);
  gemm_bt<1,0><<<(kNKPAD/128)*4, 256, 0, stream>>>(kin_bf, wkv_bf, kvf_bf,
                                                   nullptr, kKINP, kKINP/64,
                                                   4, kZIN);
  attn2_kernel<<<kNB, 256, 0, stream>>>(qv_f, kvf_bf, qin_bf, nbrm, aonf_bf);
  // z (bf16, relu, +b_out) then link-pred projections P = z @ [spw;dpw]^T
  gemm_bt<1,1><<<(kNBPAD/128)*2, 256, 0, stream>>>(aonf_bf, wo_bf, z_bf, b_out,
                                                   kZIN, kZIN/64, 2, kDEMB);
  gemm_bt<0,0><<<(kNBPAD/128)*4, 256, 0, stream>>>(z_bf, wlp_bf, P_f, nullptr,
                                                   kDEMB, kDEMB/64, 4, kZIN);
  lp_small<<<4000, 256, 0, stream>>>(P_f, lp_sb, lp_db, lp_ow, lp_ob,
                                     (float*)d_out);
}